// Round 6
// baseline (171.600 us; speedup 1.0000x reference)
//
#include <hip/hip_runtime.h>
#include <hip/hip_cooperative_groups.h>

namespace cg = cooperative_groups;

#define B_TOT   4096
#define NSTEPS  4
#define E       128
#define OUT_DIM 16
#define NMOD    64
#define KSPLIT  4
#define TILE    16
#define GRID    256

// ws layout:
//   int  cnt [4][64]        at int-offset 0
//   int  off [4][64]        at int-offset 256
//   int  perm[4][4096]      at int-offset 512
//   uint xbufP[4096][128]   at byte 67584   (2 MB, packed bf16 hi<<16|lo)
//   uint4 Wfrag[64][hi/lo][ss][c][g] at byte 2164736 (8 MB, frag-major bf16)
#define XBUF_BYTE  67584
#define WFRAG_BYTE 2164736

using frag8 = __attribute__((ext_vector_type(8))) short;   // 8 bf16
using f32x4 = __attribute__((ext_vector_type(4))) float;

__device__ __forceinline__ unsigned short f2bf(float x) {
    union { float f; unsigned u; } v; v.f = x;
    unsigned r = v.u + 0x7FFFu + ((v.u >> 16) & 1u);
    return (unsigned short)(r >> 16);
}
__device__ __forceinline__ float bf2f(unsigned short h) {
    union { unsigned u; float f; } v; v.u = ((unsigned)h) << 16;
    return v.f;
}
__device__ __forceinline__ unsigned pack2(unsigned short a, unsigned short b) {
    return (unsigned)a | ((unsigned)b << 16);
}
__device__ __forceinline__ frag8 u4frag(uint4 u) {
    union { uint4 u; frag8 f; } v; v.u = u; return v.f;
}
__device__ __forceinline__ float tanh_fast(float x) {
    return 1.0f - 2.0f / (__expf(2.0f * x) + 1.0f);
}

__global__ __launch_bounds__(256) void fused_all(
    const int* __restrict__ mids,
    const int* __restrict__ author_ids,
    const float* __restrict__ embed,
    const float* __restrict__ W,
    const float* __restrict__ bias,
    const float* __restrict__ cls_W,
    const float* __restrict__ cls_b,
    float* __restrict__ out,
    int* __restrict__ ws)
{
    const int bid = blockIdx.x;
    const int t   = threadIdx.x;

    __shared__ __align__(16) float Yl[TILE * (E + 4)];   // classifier scratch; aliased by sort
    int* h = (int*)Yl;          // [64] histogram / cursor
    int* o = h + NMOD;          // [64] offsets

    // ================= phase P: sort (blocks 0..3) + W convert (blocks 4..255) ==========
    if (bid < NSTEPS) {
        const int s = bid;
        if (t < NMOD) h[t] = 0;
        __syncthreads();
        for (int b = t; b < B_TOT; b += 256)
            atomicAdd(&h[mids[b * NSTEPS + s]], 1);
        __syncthreads();
        if (t < NMOD) {                       // wave-level exclusive scan (threads 0..63 = wave 0)
            const int v = h[t];
            int inc = v;
            #pragma unroll
            for (int d = 1; d < NMOD; d <<= 1) {
                const int nv = __shfl_up(inc, d, 64);
                if (t >= d) inc += nv;
            }
            o[t] = inc - v;
        }
        __syncthreads();
        if (t < NMOD) {
            ws[s * NMOD + t]       = h[t];    // cnt
            ws[256 + s * NMOD + t] = o[t];    // off
            h[t] = o[t];                      // cursor
        }
        __syncthreads();
        int* perm = ws + 512 + s * B_TOT;
        for (int b = t; b < B_TOT; b += 256) {
            const int m = mids[b * NSTEPS + s];
            perm[atomicAdd(&h[m], 1)] = b;
        }
    } else {
        uint4* __restrict__ wf = (uint4*)((char*)ws + WFRAG_BYTE);
        for (int q = (bid - NSTEPS) * 256 + t; q < NMOD * 2048; q += (GRID - NSTEPS) * 256) {
            const int m  = q >> 11;
            const int u  = q & 2047;           // u = ss*512 + c*4 + g
            const int ss = u >> 9;
            const int c  = (u >> 2) & 127;
            const int g  = u & 3;
            const f32x4* __restrict__ src =
                (const f32x4*)(W + (size_t)m * E * E + c * E + ss * 32 + g * 8);
            const f32x4 v0 = src[0];
            const f32x4 v1 = src[1];
            const float xf[8] = {v0.x, v0.y, v0.z, v0.w, v1.x, v1.y, v1.z, v1.w};
            unsigned short hh[8], qq[8];
            #pragma unroll
            for (int j = 0; j < 8; ++j) {
                hh[j] = f2bf(xf[j]);
                qq[j] = f2bf(xf[j] - bf2f(hh[j]));
            }
            const uint4 H = { pack2(hh[0], hh[1]), pack2(hh[2], hh[3]),
                              pack2(hh[4], hh[5]), pack2(hh[6], hh[7]) };
            const uint4 L = { pack2(qq[0], qq[1]), pack2(qq[2], qq[3]),
                              pack2(qq[4], qq[5]), pack2(qq[6], qq[7]) };
            wf[m * 4096 + u]        = H;
            wf[m * 4096 + u + 2048] = L;
        }
    }

    cg::this_grid().sync();

    // ================= phases 0..3: grouped tile GEMMs =================
    const int m = bid & (NMOD - 1);       // module: all 4 slices of m on XCD m%8
    const int k = bid >> 6;               // slice 0..3
    const int w  = t >> 6;
    const int l  = t & 63;
    const int g  = l >> 4;
    const int r0 = l & 15;
    const int c0 = 32 * w + r0;
    const int c1 = c0 + 16;

    unsigned* __restrict__ xbufP = (unsigned*)((char*)ws + XBUF_BYTE);
    const uint4* __restrict__ wf = (const uint4*)((char*)ws + WFRAG_BYTE) + m * 4096;
    const float b0 = bias[m * E + c0];
    const float b1 = bias[m * E + c1];

    for (int s = 0; s < NSTEPS; ++s) {
        const bool FIRST = (s == 0);
        const bool LAST  = (s == NSTEPS - 1);
        const int cnt = ws[s * NMOD + m];
        const int off = ws[256 + s * NMOD + m];
        const int end = off + cnt;
        const int* __restrict__ perm = ws + 512 + s * B_TOT;

        for (int base = off + k * TILE; base < end; base += KSPLIT * TILE) {
            const int nb = min(TILE, end - base);
            const bool rok = r0 < nb;
            const int pa = perm[min(base + r0, B_TOT - 1)];

            // ---- A fragments (row r0) ----
            frag8 ahi[4], alo[4];
            if (FIRST) {
                const f32x4* __restrict__ src =
                    (const f32x4*)(embed + (size_t)author_ids[pa] * E);
                #pragma unroll
                for (int ss = 0; ss < 4; ++ss) {
                    f32x4 v0 = {0.f, 0.f, 0.f, 0.f}, v1 = {0.f, 0.f, 0.f, 0.f};
                    if (rok) { v0 = src[8 * ss + 2 * g]; v1 = src[8 * ss + 2 * g + 1]; }
                    const float xf[8] = {v0.x, v0.y, v0.z, v0.w, v1.x, v1.y, v1.z, v1.w};
                    #pragma unroll
                    for (int j = 0; j < 8; ++j) {
                        const unsigned short hh = f2bf(xf[j]);
                        ahi[ss][j] = (short)hh;
                        alo[ss][j] = (short)f2bf(xf[j] - bf2f(hh));
                    }
                }
            } else {
                const uint4* __restrict__ src = (const uint4*)(xbufP + (size_t)pa * E);
                #pragma unroll
                for (int ss = 0; ss < 4; ++ss) {
                    uint4 p0 = {0, 0, 0, 0}, p1 = {0, 0, 0, 0};
                    if (rok) { p0 = src[8 * ss + 2 * g]; p1 = src[8 * ss + 2 * g + 1]; }
                    const unsigned pv[8] = {p0.x, p0.y, p0.z, p0.w, p1.x, p1.y, p1.z, p1.w};
                    #pragma unroll
                    for (int j = 0; j < 8; ++j) {
                        ahi[ss][j] = (short)(pv[j] >> 16);
                        alo[ss][j] = (short)(pv[j] & 0xFFFFu);
                    }
                }
            }

            // ---- MFMA: acc = Xhi*Whi + Xlo*Whi + Xhi*Wlo (B-frags from L2) ----
            f32x4 acc0 = {0.f, 0.f, 0.f, 0.f};
            f32x4 acc1 = {0.f, 0.f, 0.f, 0.f};
            #pragma unroll
            for (int ss = 0; ss < 4; ++ss) {
                const int u0 = ss * 512 + c0 * 4 + g;
                const int u1 = ss * 512 + c1 * 4 + g;
                const frag8 bh0 = u4frag(wf[u0]);
                const frag8 bq0 = u4frag(wf[u0 + 2048]);
                const frag8 bh1 = u4frag(wf[u1]);
                const frag8 bq1 = u4frag(wf[u1 + 2048]);
                acc0 = __builtin_amdgcn_mfma_f32_16x16x32_bf16(ahi[ss], bh0, acc0, 0, 0, 0);
                acc0 = __builtin_amdgcn_mfma_f32_16x16x32_bf16(alo[ss], bh0, acc0, 0, 0, 0);
                acc0 = __builtin_amdgcn_mfma_f32_16x16x32_bf16(ahi[ss], bq0, acc0, 0, 0, 0);
                acc1 = __builtin_amdgcn_mfma_f32_16x16x32_bf16(ahi[ss], bh1, acc1, 0, 0, 0);
                acc1 = __builtin_amdgcn_mfma_f32_16x16x32_bf16(alo[ss], bh1, acc1, 0, 0, 0);
                acc1 = __builtin_amdgcn_mfma_f32_16x16x32_bf16(ahi[ss], bq1, acc1, 0, 0, 0);
            }

            // ---- epilogue: D row = 4g + r, cols c0/c1 ----
            if (!LAST) {
                #pragma unroll
                for (int r = 0; r < 4; ++r) {
                    const int row = 4 * g + r;
                    if (row < nb) {
                        const int rb = perm[base + row];
                        const float y0 = tanh_fast(acc0[r] + b0);
                        const float y1 = tanh_fast(acc1[r] + b1);
                        const unsigned short h0 = f2bf(y0);
                        const unsigned short h1 = f2bf(y1);
                        unsigned* __restrict__ dst = xbufP + (size_t)rb * E;
                        dst[c0] = pack2(f2bf(y0 - bf2f(h0)), h0);
                        dst[c1] = pack2(f2bf(y1 - bf2f(h1)), h1);
                    }
                }
            } else {
                #pragma unroll
                for (int r = 0; r < 4; ++r) {
                    const int row = 4 * g + r;
                    Yl[row * (E + 4) + c0] = acc0[r] + b0;
                    Yl[row * (E + 4) + c1] = acc1[r] + b1;
                }
                __syncthreads();
                const int row = t >> 4, j = t & 15;
                if (row < nb) {
                    const f32x4* __restrict__ cw = (const f32x4*)(cls_W + j * E);
                    float a2 = cls_b[j];
                    #pragma unroll 8
                    for (int jj = 0; jj < 32; ++jj) {
                        const f32x4 y4 = *(const f32x4*)&Yl[row * (E + 4) + jj * 4];
                        const f32x4 w4 = cw[jj];
                        a2 += y4.x * w4.x + y4.y * w4.y + y4.z * w4.z + y4.w * w4.w;
                    }
                    out[(size_t)perm[base + row] * OUT_DIM + j] = a2;
                }
                __syncthreads();   // Yl free for next tile
            }
        }

        if (s < NSTEPS - 1) cg::this_grid().sync();
    }
}

extern "C" void kernel_launch(void* const* d_in, const int* in_sizes, int n_in,
                              void* d_out, int out_size, void* d_ws, size_t ws_size,
                              hipStream_t stream) {
    const int*   author_ids = (const int*)d_in[0];
    const int*   module_ids = (const int*)d_in[1];
    const float* embed      = (const float*)d_in[2];
    const float* W          = (const float*)d_in[3];
    const float* bias       = (const float*)d_in[4];
    const float* cls_W      = (const float*)d_in[5];
    const float* cls_b      = (const float*)d_in[6];
    float* out = (float*)d_out;
    int*   wsI = (int*)d_ws;

    void* args[] = {
        (void*)&module_ids, (void*)&author_ids, (void*)&embed, (void*)&W,
        (void*)&bias, (void*)&cls_W, (void*)&cls_b, (void*)&out, (void*)&wsI
    };
    hipLaunchCooperativeKernel((void*)fused_all, dim3(GRID), dim3(256),
                               args, 0, stream);
}

// Round 7
// 48.571 us; speedup vs baseline: 3.5330x; 3.5330x over previous
//
#include <hip/hip_runtime.h>

#define B_TOT   4096
#define NSTEPS  4
#define E       128
#define OUT_DIM 16
#define NMOD    64
#define KSPLIT  8
#define TILE    16

// ws layout (int offsets unless noted):
//   cnt [4][64]    @ int 0
//   off [4][64]    @ int 256
//   perm[4][4096]  @ int 512
//   rank[4][4096]  @ int 16896
//   permA0[4096]   @ int 33280
//   f16 XB0[4112][128] @ byte 1 MB      (x sorted for odd-reader steps)
//   f16 XB1[4112][128] @ byte 4 MB
//   uint4 Wfrag[64][hi/lo][2048] @ byte 8 MB   (f16 frag-major, 4 MB)
#define PERM_I   512
#define RANK_I   16896
#define PERMA0_I 33280
#define XB0_BYTE (1u << 20)
#define XB1_BYTE (4u << 20)
#define WF_BYTE  (8u << 20)

typedef _Float16 f16;
using f16x8 = __attribute__((ext_vector_type(8))) f16;
using f32x4 = __attribute__((ext_vector_type(4))) float;
union U4H8 { uint4 u; f16x8 h; };

__device__ __forceinline__ float tanh_fast(float x) {
    return 1.0f - 2.0f / (__expf(2.0f * x) + 1.0f);
}

// blocks 0..3: counting sort (+rank, +permA0 for s=0). blocks 4..67: W -> f16 hi/lo frag-major.
__global__ __launch_bounds__(1024) void prep_kernel(
    const int* __restrict__ mids, const int* __restrict__ author_ids,
    const float* __restrict__ W, int* __restrict__ ws)
{
    const int t = threadIdx.x;
    if (blockIdx.x < NSTEPS) {
        const int s = blockIdx.x;
        __shared__ int h[NMOD];
        __shared__ int o[NMOD];
        if (t < NMOD) h[t] = 0;
        __syncthreads();
        for (int b = t; b < B_TOT; b += 1024)
            atomicAdd(&h[mids[b * NSTEPS + s]], 1);
        __syncthreads();
        if (t < NMOD) {                       // wave-0 exclusive scan
            const int v = h[t];
            int inc = v;
            #pragma unroll
            for (int d = 1; d < NMOD; d <<= 1) {
                const int nv = __shfl_up(inc, d, 64);
                if (t >= d) inc += nv;
            }
            o[t] = inc - v;
        }
        __syncthreads();
        if (t < NMOD) {
            ws[s * NMOD + t]       = h[t];
            ws[256 + s * NMOD + t] = o[t];
            h[t] = o[t];
        }
        __syncthreads();
        int* __restrict__ perm = ws + PERM_I + s * B_TOT;
        int* __restrict__ rank = ws + RANK_I + s * B_TOT;
        for (int b = t; b < B_TOT; b += 1024) {
            const int m = mids[b * NSTEPS + s];
            const int p = atomicAdd(&h[m], 1);
            perm[p] = b;
            rank[b] = p;
        }
        if (s == 0) {
            __syncthreads();                  // perm0 complete (this block wrote it all)
            int* __restrict__ pa0 = ws + PERMA0_I;
            for (int pos = t; pos < B_TOT; pos += 1024)
                pa0[pos] = author_ids[perm[pos]];
        }
    } else {
        const int m = blockIdx.x - NSTEPS;
        uint4* __restrict__ wf = (uint4*)((char*)ws + WF_BYTE) + m * 4096;
        #pragma unroll
        for (int i = 0; i < 2; ++i) {
            const int u  = i * 1024 + t;      // frag id: ss*512 + c*4 + g
            const int ss = u >> 9;
            const int c  = (u >> 2) & 127;
            const int g  = u & 3;
            const f32x4* __restrict__ src =
                (const f32x4*)(W + (size_t)m * E * E + c * E + ss * 32 + g * 8);
            const f32x4 v0 = src[0];
            const f32x4 v1 = src[1];
            const float xf[8] = {v0.x, v0.y, v0.z, v0.w, v1.x, v1.y, v1.z, v1.w};
            U4H8 hi, lo;
            #pragma unroll
            for (int j = 0; j < 8; ++j) {
                const f16 hh = (f16)xf[j];
                hi.h[j] = hh;
                lo.h[j] = (f16)(xf[j] - (float)hh);
            }
            wf[u]        = hi.u;
            wf[u + 2048] = lo.u;
        }
    }
}

template <bool FIRST, bool LAST>
__global__ __launch_bounds__(256) void step_kernel(
    const int s,
    const int* __restrict__ ws,
    const float* __restrict__ embed,
    const float* __restrict__ bias,
    const float* __restrict__ cls_W,
    const float* __restrict__ cls_b,
    const f16* __restrict__ Xin,
    f16* __restrict__ Xout,
    const int* __restrict__ rankN,     // rank[s+1]  (unused if LAST)
    float* __restrict__ out)
{
    const int m = blockIdx.x >> 3;
    const int k = blockIdx.x & (KSPLIT - 1);
    const int t  = threadIdx.x;
    const int w  = t >> 6;
    const int l  = t & 63;
    const int g  = l >> 4;
    const int r0 = l & 15;
    const int c0 = 32 * w + r0;
    const int c1 = c0 + 16;

    // ---- loop-invariant B fragments: issue first, straight from L2 ----
    const uint4* __restrict__ wf = (const uint4*)((const char*)ws + WF_BYTE) + m * 4096;
    U4H8 BH0[4], BL0[4], BH1[4], BL1[4];
    #pragma unroll
    for (int ss = 0; ss < 4; ++ss) {
        const int u0 = ss * 512 + c0 * 4 + g;
        const int u1 = ss * 512 + c1 * 4 + g;
        BH0[ss].u = wf[u0];
        BL0[ss].u = wf[u0 + 2048];
        BH1[ss].u = wf[u1];
        BL1[ss].u = wf[u1 + 2048];
    }

    const int cnt = ws[s * NMOD + m];
    const int off = ws[256 + s * NMOD + m];
    const int start = off + k * TILE;
    const int end   = off + cnt;
    if (start >= end) return;            // uniform across block

    const float b0 = bias[m * E + c0];
    const float b1 = bias[m * E + c1];
    const int* __restrict__ permS = ws + PERM_I + s * B_TOT;
    const int* __restrict__ pa0   = ws + PERMA0_I;

    __shared__ __align__(16) float Yl[LAST ? TILE * (E + 4) : 1];

    for (int base = start; base < end; base += KSPLIT * TILE) {
        const int nb = min(TILE, end - base);
        const int rr = min(base + r0, B_TOT - 1);

        // row-mapping gather (off critical path; one per lane, shfl later)
        int dmap;
        if (!LAST) dmap = rankN[permS[rr]];
        else       dmap = permS[rr];

        // ---- A fragments (row r0, contiguous in sorted order) ----
        f16x8 A[4];
        if (FIRST) {
            const f32x4* __restrict__ src =
                (const f32x4*)(embed + (size_t)pa0[rr] * E);
            #pragma unroll
            for (int ss = 0; ss < 4; ++ss) {
                const f32x4 v0 = src[ss * 8 + 2 * g];
                const f32x4 v1 = src[ss * 8 + 2 * g + 1];
                const float xf[8] = {v0.x, v0.y, v0.z, v0.w, v1.x, v1.y, v1.z, v1.w};
                #pragma unroll
                for (int j = 0; j < 8; ++j) A[ss][j] = (f16)xf[j];
            }
        } else {
            const U4H8* __restrict__ src = (const U4H8*)(Xin + (size_t)rr * E);
            #pragma unroll
            for (int ss = 0; ss < 4; ++ss)
                A[ss] = src[ss * 4 + g].h;
        }

        // ---- 16 MFMAs: acc = A * (Whi + Wlo) ----
        f32x4 acc0 = {0.f, 0.f, 0.f, 0.f};
        f32x4 acc1 = {0.f, 0.f, 0.f, 0.f};
        #pragma unroll
        for (int ss = 0; ss < 4; ++ss) {
            acc0 = __builtin_amdgcn_mfma_f32_16x16x32_f16(A[ss], BH0[ss].h, acc0, 0, 0, 0);
            acc1 = __builtin_amdgcn_mfma_f32_16x16x32_f16(A[ss], BH1[ss].h, acc1, 0, 0, 0);
            acc0 = __builtin_amdgcn_mfma_f32_16x16x32_f16(A[ss], BL0[ss].h, acc0, 0, 0, 0);
            acc1 = __builtin_amdgcn_mfma_f32_16x16x32_f16(A[ss], BL1[ss].h, acc1, 0, 0, 0);
        }

        // ---- epilogue: D row = 4g + r, cols c0/c1 ----
        if (!LAST) {
            #pragma unroll
            for (int r = 0; r < 4; ++r) {
                const int row = 4 * g + r;
                if (row < nb) {
                    const int d = __shfl(dmap, row, 16);   // lane with l&15==row
                    f16* __restrict__ dst = Xout + (size_t)d * E;
                    dst[c0] = (f16)tanh_fast(acc0[r] + b0);
                    dst[c1] = (f16)tanh_fast(acc1[r] + b1);
                }
            }
        } else {
            #pragma unroll
            for (int r = 0; r < 4; ++r) {
                const int row = 4 * g + r;
                Yl[row * (E + 4) + c0] = acc0[r] + b0;
                Yl[row * (E + 4) + c1] = acc1[r] + b1;
            }
            __syncthreads();
            const int row = t >> 4, j = t & 15;
            if (row < nb) {
                const int outb = __shfl(dmap, row, 16);
                const f32x4* __restrict__ cw = (const f32x4*)(cls_W + j * E);
                float a2 = cls_b[j];
                #pragma unroll 8
                for (int jj = 0; jj < 32; ++jj) {
                    const f32x4 y4 = *(const f32x4*)&Yl[row * (E + 4) + jj * 4];
                    const f32x4 w4 = cw[jj];
                    a2 += y4.x * w4.x + y4.y * w4.y + y4.z * w4.z + y4.w * w4.w;
                }
                out[(size_t)outb * OUT_DIM + j] = a2;
            }
            __syncthreads();   // Yl free for next tile
        }
    }
}

extern "C" void kernel_launch(void* const* d_in, const int* in_sizes, int n_in,
                              void* d_out, int out_size, void* d_ws, size_t ws_size,
                              hipStream_t stream) {
    const int*   author_ids = (const int*)d_in[0];
    const int*   module_ids = (const int*)d_in[1];
    const float* embed      = (const float*)d_in[2];
    const float* W          = (const float*)d_in[3];
    const float* bias       = (const float*)d_in[4];
    const float* cls_W      = (const float*)d_in[5];
    const float* cls_b      = (const float*)d_in[6];
    float* out = (float*)d_out;
    int*   wsI = (int*)d_ws;
    f16*   XB0 = (f16*)((char*)d_ws + XB0_BYTE);
    f16*   XB1 = (f16*)((char*)d_ws + XB1_BYTE);

    prep_kernel<<<NSTEPS + NMOD, 1024, 0, stream>>>(module_ids, author_ids, W, wsI);

    const dim3 g(NMOD * KSPLIT), blk(256);
    // step0: embed -> XB0 (sorted for step1)
    step_kernel<true,  false><<<g, blk, 0, stream>>>(0, wsI, embed, bias, cls_W, cls_b,
        (const f16*)nullptr, XB0, wsI + RANK_I + 1 * B_TOT, out);
    // step1: XB0 -> XB1 (sorted for step2)
    step_kernel<false, false><<<g, blk, 0, stream>>>(1, wsI, embed, bias, cls_W, cls_b,
        XB0, XB1, wsI + RANK_I + 2 * B_TOT, out);
    // step2: XB1 -> XB0 (sorted for step3)
    step_kernel<false, false><<<g, blk, 0, stream>>>(2, wsI, embed, bias, cls_W, cls_b,
        XB1, XB0, wsI + RANK_I + 3 * B_TOT, out);
    // step3: XB0 -> out (fused classifier)
    step_kernel<false, true ><<<g, blk, 0, stream>>>(3, wsI, embed, bias, cls_W, cls_b,
        XB0, (f16*)nullptr, wsI, out);
}